// Round 1
// baseline (311.187 us; speedup 1.0000x reference)
//
#include <hip/hip_runtime.h>
#include <hip/hip_bf16.h>

// Layout/design notes (v2: 2-blocks/CU residency restructure):
//  - kr[u,v,c,o] = P0 + cv1*P1 + cv2*P2 - sv1*Q1 - sv2*Q2 (planes depend on u only).
//  - Block = (u, v-half, o-half), grid 512 = 2 blocks/CU (LDS 75776 B < 80 KB).
//    Planes: 5 x [64 o][64 c] bf16 (40960 B). x' tiles: chunk of 16 v x [16 np][64 c]
//    bf16 (32768 B), 4 chunks per block. Rows are exactly 64 shorts (128 B); bank
//    conflicts broken by XOR-swizzling the 16B unit: m' = m ^ (row & 7) -> 2-way max
//    on ds_read_b128 (free per m136), bijective within each row.
//  - Wave = (vgroup of 4 v, nth pair of o-tiles). Per (ntl,ks): 5 ds_read_b128 plane
//    frags, unpack once, synthesize bf16 B-frag per v (4 FMA/value),
//    mfma_f32_16x16x32_bf16. A-frag = one swizzled ds_read_b128 from xsh.
//  - C layout: col(o)=lane&15, row(np)=(lane>>4)*4+reg  [guide §3, m89/m91 verified].
//  - acc is only [4 vj][4] per ntl (stores moved inside ntl loop) to keep VGPR <= 128
//    (__launch_bounds__(512,4) => 4 waves/SIMD => 16 waves/CU).
//  - conv stores + bn_apply loads are CACHED (not NT): 128 MB intermediate fits L3.

typedef __bf16 bf16x8 __attribute__((ext_vector_type(8)));
typedef float f32x4 __attribute__((ext_vector_type(4)));

__device__ __forceinline__ unsigned pack2(float a, float b) {
    __hip_bfloat162 h = __float22bfloat162_rn(make_float2(a, b));
    return *reinterpret_cast<unsigned*>(&h);
}
__device__ __forceinline__ void unpack8(uint4 u, float* f) {
    f[0] = __uint_as_float(u.x << 16); f[1] = __uint_as_float(u.x & 0xffff0000u);
    f[2] = __uint_as_float(u.y << 16); f[3] = __uint_as_float(u.y & 0xffff0000u);
    f[4] = __uint_as_float(u.z << 16); f[5] = __uint_as_float(u.z & 0xffff0000u);
    f[6] = __uint_as_float(u.w << 16); f[7] = __uint_as_float(u.w & 0xffff0000u);
}

__global__ __launch_bounds__(512, 4) void conv_stats(
    const float* __restrict__ xr, const float* __restrict__ xi,
    const float* __restrict__ filt, float* __restrict__ out,
    float* __restrict__ gstats)
{
    __shared__ __align__(16) unsigned short pqT[5 * 4096];   // 40960 B (5 planes, swz)
    __shared__ __align__(16) unsigned short xsh[16 * 16 * 64]; // 32768 B (16 v chunk, swz)
    __shared__ float statl[512];                               // 2048 B

    const int t = threadIdx.x;
    const int gid = blockIdx.x;
    const int oh = gid >> 8;             // o-half
    const int u  = (gid & 255) >> 1;     // 0..127
    const int vh = gid & 1;              // v-half
    const int obase = oh << 6;
    const int vbase0 = vh << 6;

    unsigned* pq32 = (unsigned*)pqT;
    unsigned* xs32 = (unsigned*)xsh;

    // ---- stage P/Q planes for (u, o-half): once per block
    const float au = 6.28318530717958647692f * (float)u / 128.0f;
    float su1, cu1, su2, cu2;
    __sincosf(au, &su1, &cu1);
    __sincosf(2.0f * au, &su2, &cu2);

    #pragma unroll
    for (int k = 0; k < 4; ++k) {            // 2048 (o, c-pair) items
        int i = t + k * 512;
        int o = i & 63;                       // fastest across lanes -> coalesced filt
        int cp = i >> 6;                      // 0..31 (c = 2cp, 2cp+1)
        int g0 = (2 * cp) * 128 + obase + o;
        int g1 = g0 + 128;
        unsigned wd = o * 32 + (((cp >> 2) ^ (o & 7)) << 2) + (cp & 3); // swizzled dword
        #pragma unroll
        for (int b = 0; b < 3; ++b) {
            float f0a = filt[b * 8192 + g0],       f0b = filt[b * 8192 + g1];
            float f1a = filt[(3 + b) * 8192 + g0], f1b = filt[(3 + b) * 8192 + g1];
            float f2a = filt[(6 + b) * 8192 + g0], f2b = filt[(6 + b) * 8192 + g1];
            float Pa = fmaf(cu2, f2a, fmaf(cu1, f1a, f0a));
            float Pb = fmaf(cu2, f2b, fmaf(cu1, f1b, f0b));
            pq32[b * 2048 + wd] = pack2(Pa, Pb);
            if (b > 0) {
                float Qa = fmaf(su2, f2a, su1 * f1a);
                float Qb = fmaf(su2, f2b, su1 * f1b);
                pq32[(b + 2) * 2048 + wd] = pack2(Qa, Qb);
            }
        }
    }

    // ---- wave assignment
    const int wave = t >> 6;
    const int lane = t & 63;
    const int vg   = wave >> 1;       // 4 v's per wave: vg*4 + 0..3 (chunk-local)
    const int nth  = wave & 1;        // o-tile pair: ot = nth*2 + ntl (0..3)
    const int ln15 = lane & 15;
    const int q    = lane >> 4;
    const int swz  = ln15 & 7;
    const int part = q >> 1;
    const int nbase = (q & 1) * 4;

    // staging coords for x' chunks
    const int sv = t >> 5;            // 0..15 (chunk-local v)
    const int scp = t & 31;           // c-pair

    float ssum[2] = {0.f, 0.f}, ssq[2] = {0.f, 0.f};

    #pragma unroll 1
    for (int ch = 0; ch < 4; ++ch) {
        // ---- stage x' chunk: float2 loads, packed b32 swizzled LDS writes
        {
            const int vglob = vbase0 + ch * 16 + sv;
            unsigned wb = (sv * 16) * 32 + (((scp >> 2) ^ 0) << 2) + (scp & 3);
            #pragma unroll
            for (int n = 0; n < 8; ++n) {
                size_t gi = (((size_t)(n * 128 + u)) * 128 + vglob) * 64 + 2 * scp;
                float2 r  = *(const float2*)(xr + gi);
                float2 m2 = *(const float2*)(xi + gi);
                unsigned rp = pack2(r.x + m2.x, r.y + m2.y);
                unsigned ip = pack2(m2.x - r.x, m2.y - r.y);
                unsigned base = (sv * 16 + n) * 32 + (((scp >> 2) ^ (n & 7)) << 2) + (scp & 3);
                xs32[base] = rp;               // np = n      (r+i)
                xs32[base + 8 * 32] = ip;      // np = 8+n    (i-r), same swizzle
            }
            (void)wb;
        }
        __syncthreads();

        // ---- per-v trig for this chunk
        float cv1[4], cv2[4], nsv1[4], nsv2[4];
        #pragma unroll
        for (int vj = 0; vj < 4; ++vj) {
            float av = 6.28318530717958647692f *
                       (float)(vbase0 + ch * 16 + vg * 4 + vj) / 128.0f;
            float s1, c1, s2, c2;
            __sincosf(av, &s1, &c1);
            __sincosf(2.0f * av, &s2, &c2);
            cv1[vj] = c1; cv2[vj] = c2; nsv1[vj] = -s1; nsv2[vj] = -s2;
        }

        // ---- A-fragments (swizzled b128, register layout == MFMA A layout)
        bf16x8 af[4][2];
        #pragma unroll
        for (int vj = 0; vj < 4; ++vj) {
            const unsigned short* xrow = &xsh[((vg * 4 + vj) * 16 + ln15) * 64];
            #pragma unroll
            for (int ks = 0; ks < 2; ++ks) {
                int m = ks * 4 + q;
                af[vj][ks] = __builtin_bit_cast(bf16x8,
                    *(const uint4*)(xrow + ((m ^ swz) << 3)));
            }
        }

        // ---- main: per o-tile, synth B once per (vj,ks) from shared plane frags
        #pragma unroll
        for (int ntl = 0; ntl < 2; ++ntl) {
            const int ot = nth * 2 + ntl;
            const int o_loc = ot * 16 + ln15;
            const unsigned short* prow = &pqT[o_loc * 64];
            f32x4 acc[4];
            #pragma unroll
            for (int vj = 0; vj < 4; ++vj) acc[vj] = (f32x4){0.f, 0.f, 0.f, 0.f};

            #pragma unroll
            for (int ks = 0; ks < 2; ++ks) {
                const int m = ks * 4 + q;
                const int foff = (m ^ swz) << 3;     // (o_loc&7)==ln15&7==swz
                float P0[8], P1[8], P2[8], Q1[8], Q2[8];
                unpack8(*(const uint4*)(prow + 0 * 4096 + foff), P0);
                unpack8(*(const uint4*)(prow + 1 * 4096 + foff), P1);
                unpack8(*(const uint4*)(prow + 2 * 4096 + foff), P2);
                unpack8(*(const uint4*)(prow + 3 * 4096 + foff), Q1);
                unpack8(*(const uint4*)(prow + 4 * 4096 + foff), Q2);
                #pragma unroll
                for (int vj = 0; vj < 4; ++vj) {
                    float kr[8];
                    #pragma unroll
                    for (int j = 0; j < 8; ++j) {
                        float tv = fmaf(cv1[vj], P1[j], P0[j]);
                        tv = fmaf(cv2[vj], P2[j], tv);
                        tv = fmaf(nsv1[vj], Q1[j], tv);
                        kr[j] = fmaf(nsv2[vj], Q2[j], tv);
                    }
                    uint4 B;
                    B.x = pack2(kr[0], kr[1]); B.y = pack2(kr[2], kr[3]);
                    B.z = pack2(kr[4], kr[5]); B.w = pack2(kr[6], kr[7]);
                    acc[vj] = __builtin_amdgcn_mfma_f32_16x16x32_bf16(
                        af[vj][ks], __builtin_bit_cast(bf16x8, B), acc[vj], 0, 0, 0);
                }
            }

            // ---- store + stats for this o-tile (cached stores: out fits L3)
            const int o_glob = obase + o_loc;
            #pragma unroll
            for (int vj = 0; vj < 4; ++vj) {
                const int vglob = vbase0 + ch * 16 + vg * 4 + vj;
                size_t base = (size_t)part * 16777216 + (size_t)nbase * 2097152
                            + ((size_t)(u * 128 + vglob)) * 128 + o_glob;
                #pragma unroll
                for (int r = 0; r < 4; ++r) {
                    float y = acc[vj][r];
                    out[base + (size_t)r * 2097152] = y;
                    ssum[ntl] += y;
                    ssq[ntl] = fmaf(y, y, ssq[ntl]);
                }
            }
        }
        __syncthreads();   // xsh fully consumed before next chunk's staging
    }

    // ---- block-level stats reduction
    statl[t] = 0.f;
    __syncthreads();
    #pragma unroll
    for (int ntl = 0; ntl < 2; ++ntl) {
        int chn = part * 128 + obase + (nth * 2 + ntl) * 16 + ln15;
        atomicAdd(&statl[chn], ssum[ntl]);
        atomicAdd(&statl[256 + chn], ssq[ntl]);
    }
    __syncthreads();
    atomicAdd(&gstats[t], statl[t]);
}

// stats -> per-channel scale/shift
__global__ void bn_prep(const float* __restrict__ gstats,
                        const float* __restrict__ gr, const float* __restrict__ br,
                        const float* __restrict__ gi, const float* __restrict__ bi,
                        float* __restrict__ sc_sh)
{
    int t = threadIdx.x;
    if (t < 256) {
        int part = t >> 7, o = t & 127;
        const float inv = 1.0f / 131072.0f;
        float mean = gstats[t] * inv;
        float var  = gstats[256 + t] * inv - mean * mean;
        float g = part ? gi[o] : gr[o];
        float b = part ? bi[o] : br[o];
        float s = g * rsqrtf(var + 1e-3f);
        sc_sh[t]       = s;
        sc_sh[256 + t] = b - mean * s;
    }
}

// in-place BN + LeakyReLU(0.2): cached loads (L3-resident), NT final stores
__global__ __launch_bounds__(256) void bn_apply(float* __restrict__ out,
                                                const float* __restrict__ sc_sh)
{
    size_t base = (size_t)blockIdx.x * 256 + threadIdx.x;
    #pragma unroll
    for (int it = 0; it < 4; ++it, base += (size_t)8192 * 256) {
        size_t e = base * 4;
        int part = (int)(e >> 24);
        int o = (int)(e & 127);
        const f32x4 sc = *(const f32x4*)(sc_sh + part * 128 + o);
        const f32x4 sh = *(const f32x4*)(sc_sh + 256 + part * 128 + o);
        f32x4 x = *(const f32x4*)(out + e);
        f32x4 y;
        y[0] = fmaf(x[0], sc[0], sh[0]);
        y[1] = fmaf(x[1], sc[1], sh[1]);
        y[2] = fmaf(x[2], sc[2], sh[2]);
        y[3] = fmaf(x[3], sc[3], sh[3]);
        x[0] = y[0] >= 0.0f ? y[0] : 0.2f * y[0];
        x[1] = y[1] >= 0.0f ? y[1] : 0.2f * y[1];
        x[2] = y[2] >= 0.0f ? y[2] : 0.2f * y[2];
        x[3] = y[3] >= 0.0f ? y[3] : 0.2f * y[3];
        __builtin_nontemporal_store(x, (f32x4*)(out + e));
    }
}

extern "C" void kernel_launch(void* const* d_in, const int* in_sizes, int n_in,
                              void* d_out, int out_size, void* d_ws, size_t ws_size,
                              hipStream_t stream)
{
    const float* xr   = (const float*)d_in[0];
    const float* xi   = (const float*)d_in[1];
    const float* filt = (const float*)d_in[2];
    const float* gr   = (const float*)d_in[3];
    const float* br   = (const float*)d_in[4];
    const float* gi   = (const float*)d_in[5];
    const float* bi   = (const float*)d_in[6];
    float* out = (float*)d_out;
    float* ws  = (float*)d_ws;

    (void)hipMemsetAsync(ws, 0, 512 * sizeof(float), stream);
    conv_stats<<<dim3(512), dim3(512), 0, stream>>>(xr, xi, filt, out, ws);
    bn_prep<<<dim3(1), dim3(256), 0, stream>>>(ws, gr, br, gi, bi, ws + 512);
    bn_apply<<<dim3(8192), dim3(256), 0, stream>>>(out, ws + 512);
}